// Round 5
// baseline (1397.522 us; speedup 1.0000x reference)
//
#include <hip/hip_runtime.h>

#define NQ 14
#define NSAMP 64
#define NT 1024
#define PHYS(n) ((n) ^ (((n) >> 7) & 31))

typedef float __attribute__((ext_vector_type(2))) f2;   // (re, im)

// exchange buffers (double-buffered), expectation partials, handshake flags
__device__ f2 xbuf[2][NSAMP][16384];        // 16 MB
__device__ float pbuf[NSAMP][4][NQ];
__device__ unsigned hskf[7][NSAMP];         // zero-init; +4 per slot per launch (parity trick)

__device__ __forceinline__ f2 pkfma(f2 a, f2 b, f2 c) { return __builtin_elementwise_fma(a, b, c); }
__device__ __forceinline__ f2 sp(float x) { f2 r; r.x = x; r.y = x; return r; }
__device__ __forceinline__ f2 cmul(f2 a, f2 b) {
  f2 r; r.x = a.x * b.x - a.y * b.y; r.y = a.x * b.y + a.y * b.x; return r;
}

template<int CTRL>
__device__ __forceinline__ float dppf(float x) {
  return __int_as_float(__builtin_amdgcn_mov_dpp(__float_as_int(x), CTRL, 0xF, 0xF, true));
}
// lane butterflies: M=0 xor l0 (quad_perm), 1 xor l1, 2 xor l2 (shfl 4), 3 xor l3 (row_ror:8), 4 xor l5 (shfl 32)
template<int M>
__device__ __forceinline__ float bf(float x) {
  if constexpr (M == 0) return dppf<0xB1>(x);
  else if constexpr (M == 1) return dppf<0x4E>(x);
  else if constexpr (M == 2) return __shfl_xor(x, 4, 64);
  else if constexpr (M == 3) return dppf<0x128>(x);
  else return __shfl_xor(x, 32, 64);
}

__device__ __forceinline__ void ry_m0(f2* v, f2 cs) {
  const f2 vc = sp(cs.x), vs = sp(cs.y), vn = sp(-cs.y);
  f2 a0 = v[0], a1 = v[1];
  v[0] = pkfma(a1, vn, a0 * vc); v[1] = pkfma(a0, vs, a1 * vc);
  a0 = v[2]; a1 = v[3];
  v[2] = pkfma(a1, vn, a0 * vc); v[3] = pkfma(a0, vs, a1 * vc);
}
__device__ __forceinline__ void ry_m1(f2* v, f2 cs) {
  const f2 vc = sp(cs.x), vs = sp(cs.y), vn = sp(-cs.y);
  f2 a0 = v[0], a1 = v[2];
  v[0] = pkfma(a1, vn, a0 * vc); v[2] = pkfma(a0, vs, a1 * vc);
  a0 = v[1]; a1 = v[3];
  v[1] = pkfma(a1, vn, a0 * vc); v[3] = pkfma(a0, vs, a1 * vc);
}
template<int M>
__device__ __forceinline__ void bfly_ry(f2* v, f2 cs, int bitset) {
  const float se = bitset ? cs.y : -cs.y;
  const f2 vc = sp(cs.x), vse = sp(se);
#pragma unroll
  for (int j = 0; j < 4; ++j) {
    f2 p; p.x = bf<M>(v[j].x); p.y = bf<M>(v[j].y);
    v[j] = pkfma(p, vse, v[j] * vc);
  }
}

__device__ __forceinline__ float dot2(f2 a, f2 b) { f2 r = a * b; return r.x + r.y; }
__device__ __forceinline__ float exp_m0(const f2* v) { return dot2(v[0], v[1]) + dot2(v[2], v[3]); }
__device__ __forceinline__ float exp_m1(const f2* v) { return dot2(v[0], v[2]) + dot2(v[1], v[3]); }
template<int M>
__device__ __forceinline__ float bfly_dot(const f2* v) {
  float acc = 0.f;
#pragma unroll
  for (int j = 0; j < 4; ++j) { f2 p; p.x = bf<M>(v[j].x); p.y = bf<M>(v[j].y); acc += dot2(v[j], p); }
  return acc;
}
__device__ __forceinline__ void wred_atomic(float val, float* dst, int t) {
#pragma unroll
  for (int off = 32; off; off >>= 1) val += __shfl_down(val, off, 64);
  if ((t & 63) == 0) atomicAdd(dst, val);
}

// per-wire 2-vector u = RY(q0) * RX(n) * RY(n) |0>
__device__ __forceinline__ void wire_u(float nz, float q0, f2& u0, f2& u1) {
  float sn, cn, sy, cy;
  __sincosf(0.5f * nz, &sn, &cn);
  __sincosf(0.5f * q0, &sy, &cy);
  const float cc = cn * cn, ss = sn * sn, cs = cn * sn;
  u0.x = cy * cc - sy * cs;  u0.y = sy * cs - cy * ss;
  u1.x = sy * cc + cy * cs;  u1.y = -sy * ss - cy * cs;
}

// CZ ladder sign: parity(i & (i>>1)) over the full 14-bit index
__device__ __forceinline__ void czA(f2* v, int ibaseA) {
#pragma unroll
  for (int j = 0; j < 4; ++j) {
    const int i = ibaseA + j;
    v[j] = v[j] * sp(1.f - 2.f * (float)(__popc(i & (i >> 1)) & 1));
  }
}
__device__ __forceinline__ void czB(f2* v, int ibaseB) {
#pragma unroll
  for (int j = 0; j < 4; ++j) {
    const int i = ibaseB + (j << 7);
    v[j] = v[j] * sp(1.f - 2.f * (float)(__popc(i & (i >> 1)) & 1));
  }
}

// gates: layout A gates bits 0-6 = wires 13..7; layout B gates bits 7-13 = wires 6..0
__device__ __forceinline__ void gatesA(f2* v, const f2* csT, int L, int l) {
  const f2* cs = csT + (L - 1) * NQ;
  ry_m0(v, cs[13]); ry_m1(v, cs[12]);
  bfly_ry<0>(v, cs[11], l & 1);
  bfly_ry<1>(v, cs[10], l & 2);
  bfly_ry<2>(v, cs[9],  l & 4);
  bfly_ry<3>(v, cs[8],  l & 8);
  bfly_ry<4>(v, cs[7],  l & 32);
}
__device__ __forceinline__ void gatesB(f2* v, const f2* csT, int L, int l) {
  const f2* cs = csT + (L - 1) * NQ;
  ry_m0(v, cs[6]); ry_m1(v, cs[5]);
  bfly_ry<0>(v, cs[4], l & 1);
  bfly_ry<1>(v, cs[3], l & 2);
  bfly_ry<2>(v, cs[2], l & 4);
  bfly_ry<3>(v, cs[1], l & 8);
  bfly_ry<4>(v, cs[0], l & 32);
}

// 4-block handshake: monotonic counter, parity trick — no reset needed across launches
__device__ __forceinline__ void hsk(int phase, int s, int t) {
  __threadfence();
  __syncthreads();
  if (t == 0) {
    unsigned old = __hip_atomic_fetch_add(&hskf[phase][s], 1u, __ATOMIC_RELEASE, __HIP_MEMORY_SCOPE_AGENT);
    unsigned tgt = (old & ~3u) + 4u;
    while (__hip_atomic_load(&hskf[phase][s], __ATOMIC_ACQUIRE, __HIP_MEMORY_SCOPE_AGENT) < tgt)
      __builtin_amdgcn_s_sleep(2);
  }
  __syncthreads();
  __threadfence();
}

__global__ __launch_bounds__(NT, 4) void qsim_kernel(
    const float* __restrict__ noise, const float* __restrict__ qp,
    float* __restrict__ out) {
  __shared__ f2 stg[4096];          // 32 KiB staging
  __shared__ f2 csT[5 * NQ];
  __shared__ f2 uT[NQ][2];
  __shared__ float red[NQ];
  const int s = blockIdx.x & 63, q = blockIdx.x >> 6;   // partner blocks differ by 64 -> same XCD under %8 round-robin
  const int t = threadIdx.x, l = t & 63, w = t >> 6;

  if (t < 5 * NQ) {
    float ss, cc; __sincosf(0.5f * qp[NQ + t], &ss, &cc);
    f2 r; r.x = cc; r.y = ss; csT[t] = r;
  }
  if (t < NQ) {
    red[t] = 0.f;
    f2 u0, u1; wire_u(noise[s * NQ + t], qp[t], u0, u1);
    uT[t][0] = u0; uT[t][1] = u1;
  }

  // layout A: b0,b1=m; b2..b5=l0..l3; b6=l5; b7=l4; b8-11=w; b12,13=q
  const int ibaseA = ((l & 1) << 2) | (((l >> 1) & 1) << 3) | (((l >> 2) & 1) << 4) |
                     (((l >> 3) & 1) << 5) | (((l >> 5) & 1) << 6) | (((l >> 4) & 1) << 7) |
                     (w << 8) | (q << 12);
  // layout B: b0=l4; b1-4=w; b5,6=q; b7,8=m; b9..b12=l0..l3; b13=l5
  const int ibaseB = ((l >> 4) & 1) | (w << 1) | (q << 5) | ((l & 1) << 9) |
                     (((l >> 1) & 1) << 10) | (((l >> 2) & 1) << 11) |
                     (((l >> 3) & 1) << 12) | (((l >> 5) & 1) << 13);
  const int nA0 = ibaseA & 4095;
  const int nB0 = (ibaseB & 31) | (((ibaseB >> 7) & 127) << 5);
  __syncthreads();

#define SCATTER_A() { _Pragma("unroll") for (int j = 0; j < 4; ++j) stg[PHYS(nA0 | j)] = v[j]; }
#define GATHER_A()  { _Pragma("unroll") for (int j = 0; j < 4; ++j) v[j] = stg[PHYS(nA0 | j)]; }
#define SCATTER_B() { _Pragma("unroll") for (int j = 0; j < 4; ++j) stg[PHYS(nB0 | (j << 5))] = v[j]; }
#define GATHER_B()  { _Pragma("unroll") for (int j = 0; j < 4; ++j) v[j] = stg[PHYS(nB0 | (j << 5))]; }
#define COPYOUT_A(B_) { _Pragma("unroll") for (int k = 0; k < 4; ++k) { const int n = (t << 2) | k; \
    xbuf[B_][s][(q << 12) | n] = stg[PHYS(n)]; } }
#define COPYIN_A(B_)  { _Pragma("unroll") for (int k = 0; k < 4; ++k) { const int n = (t << 2) | k; \
    stg[PHYS(n)] = xbuf[B_][s][(q << 12) | n]; } }
#define COPYOUT_B(B_) { _Pragma("unroll") for (int k = 0; k < 4; ++k) { const int n = (t << 2) | k; \
    xbuf[B_][s][(n & 31) | (q << 5) | ((n >> 5) << 7)] = stg[PHYS(n)]; } }
#define COPYIN_B(B_)  { _Pragma("unroll") for (int k = 0; k < 4; ++k) { const int n = (t << 2) | k; \
    stg[PHYS(n)] = xbuf[B_][s][(n & 31) | (q << 5) | ((n >> 5) << 7)]; } }

  f2 v[4];
  // ---- P0: product state (encoding + layer-0 RY), in layout-A registers ----
  {
    f2 h; h.x = 1.f; h.y = 0.f;
#pragma unroll
    for (int p = 2; p < 14; ++p) h = cmul(h, uT[13 - p][(ibaseA >> p) & 1]);
#pragma unroll
    for (int j = 0; j < 4; ++j)
      v[j] = cmul(cmul(uT[13][j & 1], uT[12][(j >> 1) & 1]), h);
  }
  czA(v, ibaseA);
  gatesA(v, csT, 1, l);
  SCATTER_A(); __syncthreads(); COPYOUT_A(0); hsk(0, s, t);

  // ---- P1 [B]: B(1) + CZ(1) + B(2) ----
  COPYIN_B(0); __syncthreads(); GATHER_B();
  gatesB(v, csT, 1, l); czB(v, ibaseB); gatesB(v, csT, 2, l);
  __syncthreads(); SCATTER_B(); __syncthreads(); COPYOUT_B(1); hsk(1, s, t);

  // ---- P2 [A]: A(2) + CZ(2) + A(3) ----
  COPYIN_A(1); __syncthreads(); GATHER_A();
  gatesA(v, csT, 2, l); czA(v, ibaseA); gatesA(v, csT, 3, l);
  __syncthreads(); SCATTER_A(); __syncthreads(); COPYOUT_A(0); hsk(2, s, t);

  // ---- P3 [B]: B(3) + CZ(3) + B(4) ----
  COPYIN_B(0); __syncthreads(); GATHER_B();
  gatesB(v, csT, 3, l); czB(v, ibaseB); gatesB(v, csT, 4, l);
  __syncthreads(); SCATTER_B(); __syncthreads(); COPYOUT_B(1); hsk(3, s, t);

  // ---- P4 [A]: A(4) + CZ(4) + A(5) ----
  COPYIN_A(1); __syncthreads(); GATHER_A();
  gatesA(v, csT, 4, l); czA(v, ibaseA); gatesA(v, csT, 5, l);
  __syncthreads(); SCATTER_A(); __syncthreads(); COPYOUT_A(0); hsk(4, s, t);

  // ---- P5 [B]: B(5) + CZ(5) + <X> for wires 0-6, forward final state ----
  COPYIN_B(0); __syncthreads(); GATHER_B();
  gatesB(v, csT, 5, l); czB(v, ibaseB);
  wred_atomic(exp_m0(v),     &red[6], t);
  wred_atomic(exp_m1(v),     &red[5], t);
  wred_atomic(bfly_dot<0>(v), &red[4], t);
  wred_atomic(bfly_dot<1>(v), &red[3], t);
  wred_atomic(bfly_dot<2>(v), &red[2], t);
  wred_atomic(bfly_dot<3>(v), &red[1], t);
  wred_atomic(bfly_dot<4>(v), &red[0], t);
  __syncthreads(); SCATTER_B(); __syncthreads(); COPYOUT_B(1);
  if (t < 7) pbuf[s][q][t] = red[t];
  hsk(5, s, t);

  // ---- P6 [A]: <X> for wires 7-13 ----
  COPYIN_A(1); __syncthreads(); GATHER_A();
  wred_atomic(exp_m0(v),     &red[13], t);
  wred_atomic(exp_m1(v),     &red[12], t);
  wred_atomic(bfly_dot<0>(v), &red[11], t);
  wred_atomic(bfly_dot<1>(v), &red[10], t);
  wred_atomic(bfly_dot<2>(v), &red[9], t);
  wred_atomic(bfly_dot<3>(v), &red[8], t);
  wred_atomic(bfly_dot<4>(v), &red[7], t);
  __syncthreads();
  if (t >= 7 && t < NQ) pbuf[s][q][t] = red[t];
  hsk(6, s, t);

  if (q == 0 && t < NQ) {
    const float sum = pbuf[s][0][t] + pbuf[s][1][t] + pbuf[s][2][t] + pbuf[s][3][t];
    // reg-pair wires hold S (x2); butterfly wires hold 2S already (pairs double-counted)
    const float f = (t == 5 || t == 6 || t == 12 || t == 13) ? 2.f : 1.f;
    out[s * NQ + t] = f * sum;
  }
}

extern "C" void kernel_launch(void* const* d_in, const int* in_sizes, int n_in,
                              void* d_out, int out_size, void* d_ws, size_t ws_size,
                              hipStream_t stream) {
  const float* noise = (const float*)d_in[0];  // [64, 14]
  const float* qp    = (const float*)d_in[1];  // [6, 14]
  float* out = (float*)d_out;                  // [64, 14]
  qsim_kernel<<<256, NT, 0, stream>>>(noise, qp, out);
}

// Round 6
// 40.820 us; speedup vs baseline: 34.2364x; 34.2364x over previous
//
#include <hip/hip_runtime.h>

#define NQ 14
#define DIM (1 << NQ)       // 16384
#define NT 512
#define QD 6

typedef float2 c32;

__device__ __forceinline__ c32 cmul(c32 a, c32 b) {
  return make_float2(a.x * b.x - a.y * b.y, a.x * b.y + a.y * b.x);
}

// RY on local bit K of an NB-element register subcube (compile-time indices only)
template<int K, int NB>
__device__ __forceinline__ void apply_ry(c32* v, float c, float s) {
#pragma unroll
  for (int m = 0; m < NB / 2; ++m) {
    const int j0 = ((m >> K) << (K + 1)) | (m & ((1 << K) - 1));
    const int j1 = j0 | (1 << K);
    const c32 a0 = v[j0], a1 = v[j1];
    v[j0] = make_float2(c * a0.x - s * a1.x, c * a0.y - s * a1.y);
    v[j1] = make_float2(s * a0.x + c * a1.x, s * a0.y + c * a1.y);
  }
}

// <X> partial over local bit K: sum Re(conj(a0)*a1)
template<int K, int NB>
__device__ __forceinline__ float expv(const c32* v) {
  float acc = 0.f;
#pragma unroll
  for (int m = 0; m < NB / 2; ++m) {
    const int j0 = ((m >> K) << (K + 1)) | (m & ((1 << K) - 1));
    const int j1 = j0 | (1 << K);
    acc += v[j0].x * v[j1].x + v[j0].y * v[j1].y;
  }
  return acc;
}

__device__ __forceinline__ void wave_reduce_atomic(float val, float* dst) {
#pragma unroll
  for (int off = 32; off; off >>= 1) val += __shfl_down(val, off);
  if ((threadIdx.x & 63) == 0) atomicAdd(dst, val);
}

// per-wire 2-vector u = RY(q0) * RX(n) * RY(n) |0>
__device__ __forceinline__ void wire_u(float nz, float q0, c32& u0, c32& u1) {
  float sn, cn, sy, cy;
  __sincosf(0.5f * nz, &sn, &cn);
  __sincosf(0.5f * q0, &sy, &cy);
  const float cc = cn * cn, ss = sn * sn, cs = cn * sn;
  // g0 = (cc,-ss), g1 = (cs,-cs); u0 = cy*g0 - sy*g1; u1 = sy*g0 + cy*g1
  u0 = make_float2(cy * cc - sy * cs, sy * cs - cy * ss);
  u1 = make_float2(sy * cc + cy * cs, -sy * ss - cy * cs);
}

// ---- RY groups: A = bits 0-4 (wires 13..9), B = bits 5-9 (wires 8..4), C = bits 10-13 (wires 3..0)
__device__ __forceinline__ void ryA(c32* v, const float* __restrict__ qp, int l) {
  float c[5], s[5];
#pragma unroll
  for (int k = 0; k < 5; ++k) __sincosf(0.5f * qp[l * NQ + (13 - k)], &s[k], &c[k]);
  apply_ry<0, 32>(v, c[0], s[0]);
  apply_ry<1, 32>(v, c[1], s[1]);
  apply_ry<2, 32>(v, c[2], s[2]);
  apply_ry<3, 32>(v, c[3], s[3]);
  apply_ry<4, 32>(v, c[4], s[4]);
}
__device__ __forceinline__ void ryB(c32* v, const float* __restrict__ qp, int l) {
  float c[5], s[5];
#pragma unroll
  for (int k = 0; k < 5; ++k) __sincosf(0.5f * qp[l * NQ + (8 - k)], &s[k], &c[k]);
  apply_ry<0, 32>(v, c[0], s[0]);
  apply_ry<1, 32>(v, c[1], s[1]);
  apply_ry<2, 32>(v, c[2], s[2]);
  apply_ry<3, 32>(v, c[3], s[3]);
  apply_ry<4, 32>(v, c[4], s[4]);
}
__device__ __forceinline__ void ryC(c32 v[2][16], const float* __restrict__ qp, int l) {
  float c[4], s[4];
#pragma unroll
  for (int k = 0; k < 4; ++k) __sincosf(0.5f * qp[l * NQ + (3 - k)], &s[k], &c[k]);
#pragma unroll
  for (int r = 0; r < 2; ++r) {
    apply_ry<0, 16>(v[r], c[0], s[0]);
    apply_ry<1, 16>(v[r], c[1], s[1]);
    apply_ry<2, 16>(v[r], c[2], s[2]);
    apply_ry<3, 16>(v[r], c[3], s[3]);
  }
}

// ---- CZ ladder sign: parity(i & (i>>1)), split into thread-const ^ compile-time parts
__device__ __forceinline__ void czA(c32* v, int t) {   // i = (t<<5)|j
  const int pa = __popc(t & (t >> 1)) & 1;
  const int t0 = t & 1;
#pragma unroll
  for (int j = 0; j < 32; ++j) {
    const int sgn = pa ^ (__popc(j & (j >> 1)) & 1) ^ (((j >> 4) & 1) & t0);
    if (sgn) { v[j].x = -v[j].x; v[j].y = -v[j].y; }
  }
}
__device__ __forceinline__ void czB(c32* v, int t) {   // i = (hi<<10)|(j<<5)|lo
  const int lo = t & 31, hi = t >> 5;
  const int pb = (__popc(lo & (lo >> 1)) + __popc(hi & (hi >> 1))) & 1;
  const int lo4 = (lo >> 4) & 1, hi0 = hi & 1;
#pragma unroll
  for (int j = 0; j < 32; ++j) {
    const int sgn = pb ^ (__popc(j & (j >> 1)) & 1) ^ (lo4 & (j & 1)) ^ (((j >> 4) & 1) & hi0);
    if (sgn) { v[j].x = -v[j].x; v[j].y = -v[j].y; }
  }
}
__device__ __forceinline__ void czC(c32* v16, int o) { // i = (j<<10)|o
  const int pc = __popc(o & (o >> 1)) & 1;
  const int o9 = (o >> 9) & 1;
#pragma unroll
  for (int j = 0; j < 16; ++j) {
    const int sgn = pc ^ (__popc(j & (j >> 1)) & 1) ^ (o9 & (j & 1));
    if (sgn) { v16[j].x = -v16[j].x; v16[j].y = -v16[j].y; }
  }
}

// ---- sweeps. LDS layout swizzle: phys = i ^ ((i>>5)&31) — conflict-free in all 3 layouts.
template<int MODE>  // 0: RY(l); 1: RY(l)+CZ(l)+RY(l+1)
__device__ __forceinline__ void passA(c32* st, const float* __restrict__ qp, int t, int l) {
  c32 v[32];
  const int base = t << 5, x5 = t & 31;
#pragma unroll
  for (int j = 0; j < 32; ++j) v[j] = st[base | (j ^ x5)];
  ryA(v, qp, l);
  if (MODE == 1) { czA(v, t); ryA(v, qp, l + 1); }
#pragma unroll
  for (int j = 0; j < 32; ++j) st[base | (j ^ x5)] = v[j];
  __syncthreads();
}

template<int MODE>  // 0: RY; 1: RY+CZ+RY(l+1); 2: RY+CZ+exp partials (wires 8..4)
__device__ __forceinline__ void passB(c32* st, const float* __restrict__ qp, int t, int l,
                                      float* exps) {
  c32 v[32];
  const int bb = ((t >> 5) << 10) | (t & 31);
#pragma unroll
  for (int j = 0; j < 32; ++j) v[j] = st[bb ^ (j << 5) ^ j];
  ryB(v, qp, l);
  if (MODE == 1) { czB(v, t); ryB(v, qp, l + 1); }
  if (MODE == 2) {
    czB(v, t);
    wave_reduce_atomic(expv<0, 32>(v), &exps[8]);
    wave_reduce_atomic(expv<1, 32>(v), &exps[7]);
    wave_reduce_atomic(expv<2, 32>(v), &exps[6]);
    wave_reduce_atomic(expv<3, 32>(v), &exps[5]);
    wave_reduce_atomic(expv<4, 32>(v), &exps[4]);
  }
#pragma unroll
  for (int j = 0; j < 32; ++j) st[bb ^ (j << 5) ^ j] = v[j];
  __syncthreads();
}

template<int MODE>  // 0: RY(l); 1: RY(l)+CZ(l)+RY(l+1)
__device__ __forceinline__ void passC(c32* st, const float* __restrict__ qp, int t, int l) {
  c32 v[2][16];
#pragma unroll
  for (int r = 0; r < 2; ++r) {
    const int o = t + (r << 9);
    const int cb = o ^ (o >> 5);
#pragma unroll
    for (int j = 0; j < 16; ++j) v[r][j] = st[(j << 10) | cb];
  }
  ryC(v, qp, l);
  if (MODE == 1) {
#pragma unroll
    for (int r = 0; r < 2; ++r) czC(v[r], t + (r << 9));
    ryC(v, qp, l + 1);
  }
#pragma unroll
  for (int r = 0; r < 2; ++r) {
    const int o = t + (r << 9);
    const int cb = o ^ (o >> 5);
#pragma unroll
    for (int j = 0; j < 16; ++j) st[(j << 10) | cb] = v[r][j];
  }
  __syncthreads();
}

__global__ __launch_bounds__(NT, 2) void qsim_kernel(
    const float* __restrict__ noise, const float* __restrict__ qp,
    float* __restrict__ out) {
  __shared__ c32 st[DIM];       // 128 KiB, swizzled layout
  __shared__ float exps[NQ];
  const int b = blockIdx.x;
  const int t = threadIdx.x;
  if (t < NQ) exps[t] = 0.f;

  // ---- P0: product state = (RX*RY)(noise) + layer-0 RY, all on |0> -> pure registers ----
  c32 v[32];
  {
    c32 h = make_float2(1.f, 0.f);          // product over thread bits (global bits 5..13)
#pragma unroll
    for (int p = 5; p < 14; ++p) {
      c32 u0, u1;
      wire_u(noise[b * NQ + (13 - p)], qp[13 - p], u0, u1);
      const c32 pick = ((t >> (p - 5)) & 1) ? u1 : u0;
      h = cmul(h, pick);
    }
    {
      c32 u0, u1;
      wire_u(noise[b * NQ + 13], qp[13], u0, u1);
      v[0] = u0; v[1] = u1;
    }
#define BSTEP(P)                                                           \
    {                                                                      \
      c32 u0, u1;                                                          \
      wire_u(noise[b * NQ + (13 - (P))], qp[13 - (P)], u0, u1);            \
      _Pragma("unroll")                                                    \
      for (int j = 0; j < (1 << (P)); ++j) {                               \
        v[j | (1 << (P))] = cmul(v[j], u1);                                \
        v[j] = cmul(v[j], u0);                                             \
      }                                                                    \
    }
    BSTEP(1) BSTEP(2) BSTEP(3) BSTEP(4)
#undef BSTEP
#pragma unroll
    for (int j = 0; j < 32; ++j) v[j] = cmul(v[j], h);
  }
  czA(v, t);          // CZ of layer 0
  ryA(v, qp, 1);      // layer-1 A-group gates, still in registers
  {
    const int base = t << 5, x5 = t & 31;
#pragma unroll
    for (int j = 0; j < 32; ++j) st[base | (j ^ x5)] = v[j];
  }
  __syncthreads();

  // ---- rotated sweep schedule: 2 LDS round-trips per layer ----
  passB<0>(st, qp, t, 1, exps);
  passC<1>(st, qp, t, 1);       // + CZ1 + layer-2 C
  passA<0>(st, qp, t, 2);
  passB<1>(st, qp, t, 2, exps); // + CZ2 + layer-3 B
  passC<0>(st, qp, t, 3);
  passA<1>(st, qp, t, 3);       // + CZ3 + layer-4 A
  passB<0>(st, qp, t, 4, exps);
  passC<1>(st, qp, t, 4);       // + CZ4 + layer-5 C
  passA<0>(st, qp, t, 5);
  passB<2>(st, qp, t, 5, exps); // + CZ5 + <X> for wires 8..4, writes final state

  // ---- remaining expectations: A layout (wires 13..9), C layout (wires 3..0) ----
  {
    const int base = t << 5, x5 = t & 31;
#pragma unroll
    for (int j = 0; j < 32; ++j) v[j] = st[base | (j ^ x5)];
    wave_reduce_atomic(expv<0, 32>(v), &exps[13]);
    wave_reduce_atomic(expv<1, 32>(v), &exps[12]);
    wave_reduce_atomic(expv<2, 32>(v), &exps[11]);
    wave_reduce_atomic(expv<3, 32>(v), &exps[10]);
    wave_reduce_atomic(expv<4, 32>(v), &exps[9]);
  }
  {
    c32 w2[2][16];
#pragma unroll
    for (int r = 0; r < 2; ++r) {
      const int o = t + (r << 9);
      const int cb = o ^ (o >> 5);
#pragma unroll
      for (int j = 0; j < 16; ++j) w2[r][j] = st[(j << 10) | cb];
    }
    wave_reduce_atomic(expv<0, 16>(w2[0]) + expv<0, 16>(w2[1]), &exps[3]);
    wave_reduce_atomic(expv<1, 16>(w2[0]) + expv<1, 16>(w2[1]), &exps[2]);
    wave_reduce_atomic(expv<2, 16>(w2[0]) + expv<2, 16>(w2[1]), &exps[1]);
    wave_reduce_atomic(expv<3, 16>(w2[0]) + expv<3, 16>(w2[1]), &exps[0]);
  }
  __syncthreads();
  if (t < NQ) out[b * NQ + t] = 2.f * exps[t];
}

extern "C" void kernel_launch(void* const* d_in, const int* in_sizes, int n_in,
                              void* d_out, int out_size, void* d_ws, size_t ws_size,
                              hipStream_t stream) {
  const float* noise = (const float*)d_in[0];  // [64, 14]
  const float* qp    = (const float*)d_in[1];  // [6, 14]
  float* out = (float*)d_out;                  // [64, 14]
  qsim_kernel<<<64, NT, 0, stream>>>(noise, qp, out);
}